// Round 4
// baseline (353.366 us; speedup 1.0000x reference)
//
#include <hip/hip_runtime.h>
#include <hip/hip_bf16.h>
#include <math.h>

// Block_46643344834722: pre-norm attention block, B=512 D=2048 H=16 DH=128.
// R7: launch-graph consolidation. One prep mega-kernel does ALL 4 weight
// transposes + LN1 (non-overlapping workspace, ~142 MB of the 256 MiB ws).
// Wo GEMM drops split-K (64x64 tiles, 256 blocks, fused bias+residual ->
// x1 directly).  8 dispatches total (was 13).  GEMM keeps R6 pipeline:
// one barrier/K-step, counted vmcnt, XCD swizzle, setprio.

#define DDIM 2048
#define HHEADS 16
#define DHEAD 128
#define BROWS 512
#define LN_EPS 1e-5f

typedef __bf16 bf16x8_t __attribute__((ext_vector_type(8)));
typedef float f32x4_t __attribute__((ext_vector_type(4)));

#define GLD16(gptr, lptr)                                                     \
    __builtin_amdgcn_global_load_lds(                                         \
        (const __attribute__((address_space(1))) void*)(gptr),                \
        (__attribute__((address_space(3))) void*)(lptr), 16, 0, 0)

// ---------------------------------------------------------------- LayerNorm
__global__ __launch_bounds__(256) void ln_kernel(const float* __restrict__ x,
                                                 const float* __restrict__ g,
                                                 const float* __restrict__ b,
                                                 __bf16* __restrict__ out) {
    const int row = blockIdx.x;
    const int tid = threadIdx.x;
    const float4* x4 = (const float4*)(x + (size_t)row * DDIM);
    float4 a = x4[2 * tid];
    float4 c = x4[2 * tid + 1];
    float s  = a.x + a.y + a.z + a.w + c.x + c.y + c.z + c.w;
    float s2 = a.x*a.x + a.y*a.y + a.z*a.z + a.w*a.w
             + c.x*c.x + c.y*c.y + c.z*c.z + c.w*c.w;
    #pragma unroll
    for (int off = 32; off > 0; off >>= 1) {
        s  += __shfl_down(s, off);
        s2 += __shfl_down(s2, off);
    }
    __shared__ float ps[4], ps2[4];
    __shared__ float mean_s, rstd_s;
    const int lane = tid & 63, w = tid >> 6;
    if (lane == 0) { ps[w] = s; ps2[w] = s2; }
    __syncthreads();
    if (tid == 0) {
        float S  = ps[0] + ps[1] + ps[2] + ps[3];
        float S2 = ps2[0] + ps2[1] + ps2[2] + ps2[3];
        float m  = S * (1.0f / DDIM);
        float var = S2 * (1.0f / DDIM) - m * m;
        mean_s = m;
        rstd_s = rsqrtf(var + LN_EPS);
    }
    __syncthreads();
    const float m = mean_s, r = rstd_s;
    const float4* g4 = (const float4*)g;
    const float4* b4 = (const float4*)b;
    float4 ga = g4[2 * tid], gb = g4[2 * tid + 1];
    float4 ba = b4[2 * tid], bb = b4[2 * tid + 1];
    bf16x8_t o;
    o[0] = (__bf16)((a.x - m) * r * ga.x + ba.x);
    o[1] = (__bf16)((a.y - m) * r * ga.y + ba.y);
    o[2] = (__bf16)((a.z - m) * r * ga.z + ba.z);
    o[3] = (__bf16)((a.w - m) * r * ga.w + ba.w);
    o[4] = (__bf16)((c.x - m) * r * gb.x + bb.x);
    o[5] = (__bf16)((c.y - m) * r * gb.y + bb.y);
    o[6] = (__bf16)((c.z - m) * r * gb.z + bb.z);
    o[7] = (__bf16)((c.w - m) * r * gb.w + bb.w);
    *(bf16x8_t*)(out + (size_t)row * DDIM + tid * 8) = o;
}

// ---------------------------------------------------------------- prep mega
// One dispatch: all 4 weight transposes (fp32 [R,C] -> bf16 [C,R]) + LN1.
// blocks: [0,3072) qkv heads | [3072,4096) Wo | [4096,8192) W1 |
//         [8192,12288) W2 | [12288,12800) LN rows.
__global__ __launch_bounds__(256) void prep_kernel(
    const float* __restrict__ Wq, const float* __restrict__ Wk,
    const float* __restrict__ Wv, const float* __restrict__ Wo,
    const float* __restrict__ W1, const float* __restrict__ W2,
    const float* __restrict__ x, const float* __restrict__ g1,
    const float* __restrict__ be1,
    __bf16* __restrict__ bt_qkv, __bf16* __restrict__ Wot,
    __bf16* __restrict__ W1t, __bf16* __restrict__ W2t,
    __bf16* __restrict__ h) {
    __shared__ __align__(16) float tile[64 * 65];
    const int bid = blockIdx.x;
    const int t = threadIdx.x;
    if (bid < 12288) {
        const float* src;
        __bf16* dst;
        int R, C, r0, c0;
        if (bid < 3072) {
            const int z = bid >> 6, rem = bid & 63;
            const int which = z >> 4, hd = z & 15;
            src = ((which == 0) ? Wq : (which == 1) ? Wk : Wv) +
                  (size_t)hd * DDIM * DHEAD;
            dst = bt_qkv + (size_t)which * DDIM * DDIM +
                  (size_t)hd * DDIM * DHEAD;
            R = DDIM; C = DHEAD;
            c0 = (rem & 1) * 64; r0 = (rem >> 1) * 64;
        } else if (bid < 4096) {
            const int local = bid - 3072;
            src = Wo; dst = Wot; R = DDIM; C = DDIM;
            c0 = (local & 31) * 64; r0 = (local >> 5) * 64;
        } else if (bid < 8192) {
            const int local = bid - 4096;
            src = W1; dst = W1t; R = DDIM; C = 4 * DDIM;
            c0 = (local & 127) * 64; r0 = (local >> 7) * 64;
        } else {
            const int local = bid - 8192;
            src = W2; dst = W2t; R = 4 * DDIM; C = DDIM;
            c0 = (local & 31) * 64; r0 = (local >> 5) * 64;
        }
        const int rr = t >> 4, cc = (t & 15) * 4;
        #pragma unroll
        for (int p = 0; p < 4; p++) {
            const float4 v =
                *(const float4*)(src + (size_t)(r0 + rr + 16 * p) * C + c0 + cc);
            tile[(rr + 16 * p) * 65 + cc]     = v.x;
            tile[(rr + 16 * p) * 65 + cc + 1] = v.y;
            tile[(rr + 16 * p) * 65 + cc + 2] = v.z;
            tile[(rr + 16 * p) * 65 + cc + 3] = v.w;
        }
        __syncthreads();
        const int slot = t & 7;
        #pragma unroll
        for (int p = 0; p < 2; p++) {
            const int c = (t >> 3) + 32 * p;
            bf16x8_t o;
            #pragma unroll
            for (int j = 0; j < 8; j++)
                o[j] = (__bf16)tile[(slot * 8 + j) * 65 + c];
            *(bf16x8_t*)(dst + (size_t)(c0 + c) * R + r0 + slot * 8) = o;
        }
    } else {
        // ---- LN1: h[row] = LN(x[row]) ----
        const int row = bid - 12288;
        const float4* x4 = (const float4*)(x + (size_t)row * DDIM);
        float4 a = x4[2 * t];
        float4 c = x4[2 * t + 1];
        float s  = a.x + a.y + a.z + a.w + c.x + c.y + c.z + c.w;
        float s2 = a.x*a.x + a.y*a.y + a.z*a.z + a.w*a.w
                 + c.x*c.x + c.y*c.y + c.z*c.z + c.w*c.w;
        #pragma unroll
        for (int off = 32; off > 0; off >>= 1) {
            s  += __shfl_down(s, off);
            s2 += __shfl_down(s2, off);
        }
        const int lane = t & 63, w = t >> 6;
        if (lane == 0) { tile[w] = s; tile[8 + w] = s2; }
        __syncthreads();
        if (t == 0) {
            float S  = tile[0] + tile[1] + tile[2] + tile[3];
            float S2 = tile[8] + tile[9] + tile[10] + tile[11];
            float m  = S * (1.0f / DDIM);
            float var = S2 * (1.0f / DDIM) - m * m;
            tile[16] = m;
            tile[17] = rsqrtf(var + LN_EPS);
        }
        __syncthreads();
        const float m = tile[16], r = tile[17];
        const float4* g4 = (const float4*)g1;
        const float4* b4 = (const float4*)be1;
        float4 ga = g4[2 * t], gb = g4[2 * t + 1];
        float4 ba = b4[2 * t], bb = b4[2 * t + 1];
        bf16x8_t o;
        o[0] = (__bf16)((a.x - m) * r * ga.x + ba.x);
        o[1] = (__bf16)((a.y - m) * r * ga.y + ba.y);
        o[2] = (__bf16)((a.z - m) * r * ga.z + ba.z);
        o[3] = (__bf16)((a.w - m) * r * ga.w + ba.w);
        o[4] = (__bf16)((c.x - m) * r * gb.x + bb.x);
        o[5] = (__bf16)((c.y - m) * r * gb.y + bb.y);
        o[6] = (__bf16)((c.z - m) * r * gb.z + bb.z);
        o[7] = (__bf16)((c.w - m) * r * gb.w + bb.w);
        *(bf16x8_t*)(h + (size_t)row * DDIM + t * 8) = o;
    }
}

// ---------------------------------------------------------------- GEMM (B^T)
// C[M,N] = A[M,K] @ Bt[N,K]^T (+bias +Res, relu?).  bf16 in, fp32 acc.
// TMxTN tile, 512 threads (8 waves: 4 wave-tiles x 2 k-halves).
// BK=64 stages, both-sides XOR swizzle (pre-swizzled global source,
// swizzled ds_read_b128 -> 2-way banks = free).
// ONE barrier per K-step: circular DEPTH=4; after the barrier refill the
// slot consumed LAST step; counted vmcnt with end-taper.
// SPLITZ>1: blockIdx.z takes K/SPLITZ slice, writes raw fp32 partials.
template <int TM, int TN, int SPLITZ, int OUT_BF16, int RELU, int RES, int BIAS3>
__global__ __launch_bounds__(512) void gemm_bt(
    const __bf16* __restrict__ A, int K,
    const __bf16* __restrict__ Bt,
    const float* __restrict__ bias, const float* __restrict__ biasB,
    const float* __restrict__ biasC,
    const float* __restrict__ Res,
    void* __restrict__ Cout, int N) {
    constexpr int DEPTH = 4;
    constexpr int STG = (TM + TN) * 64;  // bf16 elems per stage (BK=64)
    __shared__ __align__(16) __bf16 smem[DEPTH * STG];

    const int tid = threadIdx.x;
    const int w = tid >> 6, lane = tid & 63;

    // ---- XCD-aware block swizzle (requires gridDim.x % 8 == 0) ----
    const int gx = gridDim.x, gy = gridDim.y, gz = gridDim.z;
    int l = blockIdx.x + gx * (blockIdx.y + gy * blockIdx.z);
    const int xcd = l & 7;
    int i0 = l >> 3;
    const int by = i0 % gy; i0 /= gy;
    const int bz = i0 % gz; i0 /= gz;
    const int bx = xcd * (gx >> 3) + i0;

    const int m0 = by * TM, n0 = bx * TN;

    const int Kloc = K / SPLITZ;
    const int kb = bz * Kloc;
    const int NK = Kloc / 64;

    constexpr int NT = (TM + TN) / 8;  // 8-row (1KB) chunks per stage
    constexpr int NI = NT / 8;         // chunks per wave

    // staging: chunk t covers rows 8t..8t+7 (A rows then B rows).
    // lane l -> row 8t+(l>>3); source k-slot pre-swizzled (l&7)^(l>>3).
    const int srow = lane >> 3;
    const int sslot = (lane & 7) ^ srow;

    const __bf16* srcs[NI];
    int toff[NI];
    #pragma unroll
    for (int i = 0; i < NI; i++) {
        const int tt = w + 8 * i;
        toff[i] = tt * 512;  // 8 rows * 64 elems
        const int r = tt * 8 + srow;
        srcs[i] = (r < TM)
                      ? A + (size_t)(m0 + r) * K + kb + sslot * 8
                      : Bt + (size_t)(n0 + r - TM) * K + kb + sslot * 8;
    }

    constexpr int MI = TM / 32, NJ = TN / 32;  // wave-tile (TM/2)x(TN/2)
    const int wg = w & 3, kh = w >> 2;         // wave-tile id, k-half id
    const int wm = (wg >> 1) * (TM / 2), wn = (wg & 1) * (TN / 2);
    const int fm = lane & 15, quad = lane >> 4;
    const int f7 = fm & 7;

    // fragment LDS byte offsets within a stage (own k-half only):
    // byte = row*128 + ((kh*4+quad) ^ (row&7))*16
    const int sl = ((kh * 4 + quad) ^ f7) * 16;
    int aoff[MI], boff[NJ];
    #pragma unroll
    for (int i = 0; i < MI; i++)
        aoff[i] = (wm + 16 * i + fm) * 128 + sl;
    #pragma unroll
    for (int j = 0; j < NJ; j++)
        boff[j] = (TM + wn + 16 * j + fm) * 128 + sl;

    f32x4_t acc[MI][NJ] = {};

    // prologue: fill all DEPTH stages
    #pragma unroll
    for (int d = 0; d < DEPTH; d++)
        #pragma unroll
        for (int i = 0; i < NI; i++)
            GLD16(srcs[i] + d * 64, smem + d * STG + toff[i]);

    for (int ks = 0; ks < NK; ks++) {
        const char* st = (const char*)smem + (ks % DEPTH) * (STG * 2);
        // single sync point: slot ks ready AND all waves done reading ks-1.
        if (ks < NK - 2)
            asm volatile("s_waitcnt vmcnt(%0)\n\ts_barrier"
                         :: "i"((DEPTH - 2) * NI) : "memory");
        else if (ks == NK - 2)
            asm volatile("s_waitcnt vmcnt(%0)\n\ts_barrier"
                         :: "i"(NI) : "memory");
        else
            asm volatile("s_waitcnt vmcnt(0)\n\ts_barrier" ::: "memory");

        // refill the slot consumed last step (data for step ks+DEPTH-1).
        if (ks >= 1 && ks + DEPTH - 1 < NK) {
            __bf16* dst = smem + ((ks - 1) % DEPTH) * STG;
            #pragma unroll
            for (int i = 0; i < NI; i++)
                GLD16(srcs[i] + (size_t)(ks + DEPTH - 1) * 64, dst + toff[i]);
        }

        bf16x8_t a[MI], b[NJ];
        #pragma unroll
        for (int i = 0; i < MI; i++)
            a[i] = *(const bf16x8_t*)(st + aoff[i]);
        #pragma unroll
        for (int j = 0; j < NJ; j++)
            b[j] = *(const bf16x8_t*)(st + boff[j]);
        __builtin_amdgcn_s_setprio(1);
        #pragma unroll
        for (int i = 0; i < MI; i++)
            #pragma unroll
            for (int j = 0; j < NJ; j++)
                acc[i][j] = __builtin_amdgcn_mfma_f32_16x16x32_bf16(
                    a[i], b[j], acc[i][j], 0, 0, 0);
        __builtin_amdgcn_s_setprio(0);
    }

    // ---- merge the two k-half accumulators through LDS (reuses stages) ----
    char* mrg = (char*)smem + wg * (MI * NJ * 64 * 16);
    __syncthreads();  // all reads of the final slot complete before reuse
    if (kh == 1) {
        #pragma unroll
        for (int i = 0; i < MI; i++)
            #pragma unroll
            for (int j = 0; j < NJ; j++)
                *(f32x4_t*)(mrg + (((i * NJ + j) * 64) + lane) * 16) = acc[i][j];
    }
    __syncthreads();
    if (kh == 1) return;
    #pragma unroll
    for (int i = 0; i < MI; i++)
        #pragma unroll
        for (int j = 0; j < NJ; j++) {
            const f32x4_t p = *(const f32x4_t*)(mrg + (((i * NJ + j) * 64) + lane) * 16);
            acc[i][j][0] += p[0]; acc[i][j][1] += p[1];
            acc[i][j][2] += p[2]; acc[i][j][3] += p[3];
        }

    // epilogue: C/D layout col=fm, row=quad*4+r  (waves 0..3 only)
    if (SPLITZ > 1) {
        float* P = (float*)Cout + (size_t)bz * (gy * TM) * N;
        #pragma unroll
        for (int i = 0; i < MI; i++)
            #pragma unroll
            for (int j = 0; j < NJ; j++) {
                const int col = n0 + wn + 16 * j + fm;
                #pragma unroll
                for (int r = 0; r < 4; r++) {
                    const int row = m0 + wm + 16 * i + quad * 4 + r;
                    P[(size_t)row * N + col] = acc[i][j][r];
                }
            }
    } else {
        const float* bp = bias;
        if (BIAS3) {  // q|k|v segment select, uniform per block
            const int seg = n0 >> 11;
            bp = (seg == 0) ? bias : (seg == 1) ? biasB : biasC;
        }
        #pragma unroll
        for (int i = 0; i < MI; i++)
            #pragma unroll
            for (int j = 0; j < NJ; j++) {
                const int col = n0 + wn + 16 * j + fm;
                const float bcol = BIAS3 ? bp[col & 2047] : bp[col];
                #pragma unroll
                for (int r = 0; r < 4; r++) {
                    const int row = m0 + wm + 16 * i + quad * 4 + r;
                    float val = acc[i][j][r] + bcol;
                    if (RES) val += Res[(size_t)row * N + col];
                    if (RELU) val = fmaxf(val, 0.0f);
                    if (OUT_BF16)
                        ((__bf16*)Cout)[(size_t)row * N + col] = (__bf16)val;
                    else
                        ((float*)Cout)[(size_t)row * N + col] = val;
                }
            }
    }
}

// ---------------------------------------------------------------- split-K sum
// out[512,2048] = Res + bias(per-col) + sum_s part[s]   (float4 per thread)
template <int NS>
__global__ __launch_bounds__(256) void reduce_splitk(
    const float* __restrict__ part, const float* __restrict__ Res,
    const float* __restrict__ bias, float* __restrict__ out) {
    const int idx = blockIdx.x * 256 + threadIdx.x;  // 0..262143 float4s
    const float4 b4 = ((const float4*)bias)[idx & 511];
    float4 r = ((const float4*)Res)[idx];
    #pragma unroll
    for (int s = 0; s < NS; s++) {
        const float4 p = ((const float4*)part)[(size_t)s * 262144 + idx];
        r.x += p.x; r.y += p.y; r.z += p.z; r.w += p.w;
    }
    r.x += b4.x; r.y += b4.y; r.z += b4.z; r.w += b4.w;
    ((float4*)out)[idx] = r;
}

// ---------------------------------------------------------------- Attention
// qkv bf16 [512, 6144] (q|k|v per row, each [H,DH]); o bf16 [512, 2048].
__global__ __launch_bounds__(128) void attn_kernel(
    const __bf16* __restrict__ qkv, __bf16* __restrict__ o) {
    const int bh = blockIdx.x;  // b*H + h
    const int b = bh >> 4, h = bh & 15;
    const size_t base = (size_t)b * (3 * DDIM) + h * DHEAD;
    const int tid = threadIdx.x;
    __shared__ float ks[DHEAD], vs[DHEAD];
    ks[tid] = (float)qkv[base + DDIM + tid];
    vs[tid] = (float)qkv[base + 2 * DDIM + tid];
    __syncthreads();
    const float a = (float)qkv[base + tid] * 0.08838834764831845f;  // /sqrt(128)
    float den = 0.0f, num = 0.0f;
    #pragma unroll 8
    for (int j = 0; j < DHEAD; j++) {
        float e = __expf(a * ks[j]);
        den += e;
        num += e * vs[j];
    }
    o[(size_t)b * DDIM + h * DHEAD + tid] = (__bf16)(num / den);
}

// ---------------------------------------------------------------- launch
extern "C" void kernel_launch(void* const* d_in, const int* in_sizes, int n_in,
                              void* d_out, int out_size, void* d_ws, size_t ws_size,
                              hipStream_t stream) {
    const float* x   = (const float*)d_in[0];
    const float* Wq  = (const float*)d_in[1];
    const float* bq  = (const float*)d_in[2];
    const float* Wk  = (const float*)d_in[3];
    const float* bk  = (const float*)d_in[4];
    const float* Wv  = (const float*)d_in[5];
    const float* bv  = (const float*)d_in[6];
    const float* Wo  = (const float*)d_in[7];
    const float* bo  = (const float*)d_in[8];
    const float* W1  = (const float*)d_in[9];
    const float* b1  = (const float*)d_in[10];
    const float* W2  = (const float*)d_in[11];
    const float* b2  = (const float*)d_in[12];
    const float* g1  = (const float*)d_in[13];
    const float* be1 = (const float*)d_in[14];
    const float* g2  = (const float*)d_in[15];
    const float* be2 = (const float*)d_in[16];
    float* out = (float*)d_out;

    // ---- workspace layout (bytes), NON-overlapping (~142 MB of 256 MiB) ----
    char* base = (char*)d_ws;
    __bf16* bt_qkv = (__bf16*)(base + 0);             // [6144,2048]  25,165,824
    __bf16* Wot    = (__bf16*)(base + 25165824);      // [2048,2048]   8,388,608
    __bf16* W1t    = (__bf16*)(base + 33554432);      // [8192,2048]  33,554,432
    __bf16* W2t    = (__bf16*)(base + 67108864);      // [2048,8192]  33,554,432
    __bf16* h      = (__bf16*)(base + 100663296);     // [512,2048]    2,097,152
    __bf16* qkv    = (__bf16*)(base + 102760448);     // [512,6144]    6,291,456
    __bf16* ob     = (__bf16*)(base + 109051904);     // [512,2048]    2,097,152
    float*  x1     = (float*)(base + 111149056);      // [512,2048]    4,194,304
    __bf16* h2     = (__bf16*)(base + 115343360);     // [512,2048]    2,097,152
    __bf16* t      = (__bf16*)(base + 117440512);     // [512,8192]    8,388,608
    float*  w2P    = (float*)(base + 125829120);      // [4][512,2048] 16,777,216

    // 1. prep: all weight transposes (bf16 B^T) + h = LN(x)
    prep_kernel<<<12800, 256, 0, stream>>>(Wq, Wk, Wv, Wo, W1, W2, x, g1, be1,
                                           bt_qkv, Wot, W1t, W2t, h);

    // 2. qkv = h @ [Wq|Wk|Wv] + [bq|bk|bv]   -> bf16 [512,6144]
    gemm_bt<128, 128, 1, 1, 0, 0, 1><<<dim3(48, 4), 512, 0, stream>>>(
        h, DDIM, bt_qkv, bq, bk, bv, nullptr, qkv, 3 * DDIM);

    // 3. per-sample outer-product attention
    attn_kernel<<<BROWS * HHEADS, 128, 0, stream>>>(qkv, ob);

    // 4. x1 = x + ob @ Wo + bo   (64x64 tiles, 256 blocks, no split-K)
    gemm_bt<64, 64, 1, 0, 0, 1, 0><<<dim3(32, 8), 512, 0, stream>>>(
        ob, DDIM, Wot, bo, nullptr, nullptr, x, x1, DDIM);

    // 5. h2 = LN(x1)
    ln_kernel<<<BROWS, 256, 0, stream>>>(x1, g2, be2, h2);

    // 6. t = relu(h2 @ W1 + b1)  -> bf16 [512,8192]
    gemm_bt<128, 128, 1, 1, 1, 0, 0><<<dim3(64, 4), 512, 0, stream>>>(
        h2, DDIM, W1t, b1, nullptr, nullptr, nullptr, t, 4 * DDIM);

    // 7. w2P = t @ W2 partials   (split-K=4, full chip)
    gemm_bt<128, 128, 4, 0, 0, 0, 0><<<dim3(16, 4, 4), 512, 0, stream>>>(
        t, 4 * DDIM, W2t, nullptr, nullptr, nullptr, nullptr, w2P, DDIM);

    // 8. out = x1 + sum(w2P) + b2
    reduce_splitk<4><<<1024, 256, 0, stream>>>(w2P, x1, b2, out);
}

// Round 5
// 351.342 us; speedup vs baseline: 1.0058x; 1.0058x over previous
//
#include <hip/hip_runtime.h>
#include <hip/hip_bf16.h>
#include <math.h>

// Block_46643344834722: pre-norm attention block, B=512 D=2048 H=16 DH=128.
// R8: bandwidth-shaped transpose in prep (column-strip loads, bf16-in-LDS
// [64][256] with XOR swizzle ^((c&31)<<4), ds_write_b64 / ds_read_b128,
// 256B-segment stores).  qkv GEMM retiled 64x192 -> 256 blocks (full chip),
// per-column bias select.  GEMM pipeline otherwise unchanged (R6 structure).

#define DDIM 2048
#define HHEADS 16
#define DHEAD 128
#define BROWS 512
#define LN_EPS 1e-5f

typedef __bf16 bf16x8_t __attribute__((ext_vector_type(8)));
typedef __bf16 bf16x4_t __attribute__((ext_vector_type(4)));
typedef float f32x4_t __attribute__((ext_vector_type(4)));

#define GLD16(gptr, lptr)                                                     \
    __builtin_amdgcn_global_load_lds(                                         \
        (const __attribute__((address_space(1))) void*)(gptr),                \
        (__attribute__((address_space(3))) void*)(lptr), 16, 0, 0)

// ---------------------------------------------------------------- LayerNorm
__global__ __launch_bounds__(256) void ln_kernel(const float* __restrict__ x,
                                                 const float* __restrict__ g,
                                                 const float* __restrict__ b,
                                                 __bf16* __restrict__ out) {
    const int row = blockIdx.x;
    const int tid = threadIdx.x;
    const float4* x4 = (const float4*)(x + (size_t)row * DDIM);
    float4 a = x4[2 * tid];
    float4 c = x4[2 * tid + 1];
    float s  = a.x + a.y + a.z + a.w + c.x + c.y + c.z + c.w;
    float s2 = a.x*a.x + a.y*a.y + a.z*a.z + a.w*a.w
             + c.x*c.x + c.y*c.y + c.z*c.z + c.w*c.w;
    #pragma unroll
    for (int off = 32; off > 0; off >>= 1) {
        s  += __shfl_down(s, off);
        s2 += __shfl_down(s2, off);
    }
    __shared__ float ps[4], ps2[4];
    __shared__ float mean_s, rstd_s;
    const int lane = tid & 63, w = tid >> 6;
    if (lane == 0) { ps[w] = s; ps2[w] = s2; }
    __syncthreads();
    if (tid == 0) {
        float S  = ps[0] + ps[1] + ps[2] + ps[3];
        float S2 = ps2[0] + ps2[1] + ps2[2] + ps2[3];
        float m  = S * (1.0f / DDIM);
        float var = S2 * (1.0f / DDIM) - m * m;
        mean_s = m;
        rstd_s = rsqrtf(var + LN_EPS);
    }
    __syncthreads();
    const float m = mean_s, r = rstd_s;
    const float4* g4 = (const float4*)g;
    const float4* b4 = (const float4*)b;
    float4 ga = g4[2 * tid], gb = g4[2 * tid + 1];
    float4 ba = b4[2 * tid], bb = b4[2 * tid + 1];
    bf16x8_t o;
    o[0] = (__bf16)((a.x - m) * r * ga.x + ba.x);
    o[1] = (__bf16)((a.y - m) * r * ga.y + ba.y);
    o[2] = (__bf16)((a.z - m) * r * ga.z + ba.z);
    o[3] = (__bf16)((a.w - m) * r * ga.w + ba.w);
    o[4] = (__bf16)((c.x - m) * r * gb.x + bb.x);
    o[5] = (__bf16)((c.y - m) * r * gb.y + bb.y);
    o[6] = (__bf16)((c.z - m) * r * gb.z + bb.z);
    o[7] = (__bf16)((c.w - m) * r * gb.w + bb.w);
    *(bf16x8_t*)(out + (size_t)row * DDIM + tid * 8) = o;
}

// ---------------------------------------------------------------- prep mega
// Transposes (fp32 [R,C] -> bf16 [C,R]) in 256x64 tiles + LN1.
// blocks: [0,768) qkv heads | [768,1024) Wo | [1024,2048) W1 |
//         [2048,3072) W2 | [3072,3584) LN rows.
// Column-strip loads (4B x 64 lanes = 256B/instr), cvt to bf16, pack 4 rows,
// ds_write_b64 into transposed LDS [64 cols][256 rows] bf16 with swizzle
// byte ^= ((c&31)<<4); read back ds_read_b128 (conflict-free), store 16B
// chunks so each wave-instr writes 4 x 256B contiguous segments.
__global__ __launch_bounds__(256) void prep_kernel(
    const float* __restrict__ Wq, const float* __restrict__ Wk,
    const float* __restrict__ Wv, const float* __restrict__ Wo,
    const float* __restrict__ W1, const float* __restrict__ W2,
    const float* __restrict__ x, const float* __restrict__ g1,
    const float* __restrict__ be1,
    __bf16* __restrict__ bt_qkv, __bf16* __restrict__ Wot,
    __bf16* __restrict__ W1t, __bf16* __restrict__ W2t,
    __bf16* __restrict__ h) {
    __shared__ __align__(16) char shmem[32768];
    const int bid = blockIdx.x;
    const int t = threadIdx.x;
    if (bid < 3072) {
        const float* src;
        __bf16* dst;
        int R, C, r0, c0;
        if (bid < 768) {
            const int mat = bid >> 4, rem = bid & 15;
            const int which = mat >> 4, hd = mat & 15;
            src = ((which == 0) ? Wq : (which == 1) ? Wk : Wv) +
                  (size_t)hd * DDIM * DHEAD;
            dst = bt_qkv + (size_t)which * DDIM * DDIM +
                  (size_t)hd * DDIM * DHEAD;
            R = DDIM; C = DHEAD;
            r0 = (rem >> 1) * 256; c0 = (rem & 1) * 64;
        } else if (bid < 1024) {
            const int local = bid - 768;
            src = Wo; dst = Wot; R = DDIM; C = DDIM;
            r0 = (local >> 5) * 256; c0 = (local & 31) * 64;
        } else if (bid < 2048) {
            const int local = bid - 1024;
            src = W1; dst = W1t; R = DDIM; C = 4 * DDIM;
            r0 = (local >> 7) * 256; c0 = (local & 127) * 64;
        } else {
            const int local = bid - 2048;
            src = W2; dst = W2t; R = 4 * DDIM; C = DDIM;
            r0 = (local >> 5) * 256; c0 = (local & 31) * 64;
        }
        const int w = t >> 6, l = t & 63;
        const int c = l;                  // src col handled by this lane
        const int sw = (c & 31) << 4;
        const float* sp = src + (size_t)r0 * C + c0 + c;
        #pragma unroll
        for (int g = 0; g < 16; g++) {
            const int rl = g * 16 + w * 4;  // local row base (4 rows)
            const float v0 = sp[(size_t)(rl + 0) * C];
            const float v1 = sp[(size_t)(rl + 1) * C];
            const float v2 = sp[(size_t)(rl + 2) * C];
            const float v3 = sp[(size_t)(rl + 3) * C];
            bf16x4_t u;
            u[0] = (__bf16)v0; u[1] = (__bf16)v1;
            u[2] = (__bf16)v2; u[3] = (__bf16)v3;
            *(bf16x4_t*)(shmem + c * 512 + ((rl * 2) ^ sw)) = u;
        }
        __syncthreads();
        #pragma unroll
        for (int q = 0; q < 8; q++) {
            const int co = w * 16 + (q & 3) * 4 + ((l >> 4) & 3);
            const int chunk = (l & 15) + (q >> 2) * 16;  // 16B chunk in row
            const int swo = (co & 31) << 4;
            const bf16x8_t o =
                *(const bf16x8_t*)(shmem + co * 512 + ((chunk * 16) ^ swo));
            *(bf16x8_t*)(dst + (size_t)(c0 + co) * R + r0 + chunk * 8) = o;
        }
    } else {
        // ---- LN1: h[row] = LN(x[row]) ----
        float* tile = (float*)shmem;
        const int row = bid - 3072;
        const float4* x4 = (const float4*)(x + (size_t)row * DDIM);
        float4 a = x4[2 * t];
        float4 c = x4[2 * t + 1];
        float s  = a.x + a.y + a.z + a.w + c.x + c.y + c.z + c.w;
        float s2 = a.x*a.x + a.y*a.y + a.z*a.z + a.w*a.w
                 + c.x*c.x + c.y*c.y + c.z*c.z + c.w*c.w;
        #pragma unroll
        for (int off = 32; off > 0; off >>= 1) {
            s  += __shfl_down(s, off);
            s2 += __shfl_down(s2, off);
        }
        const int lane = t & 63, w = t >> 6;
        if (lane == 0) { tile[w] = s; tile[8 + w] = s2; }
        __syncthreads();
        if (t == 0) {
            float S  = tile[0] + tile[1] + tile[2] + tile[3];
            float S2 = tile[8] + tile[9] + tile[10] + tile[11];
            float m  = S * (1.0f / DDIM);
            float var = S2 * (1.0f / DDIM) - m * m;
            tile[16] = m;
            tile[17] = rsqrtf(var + LN_EPS);
        }
        __syncthreads();
        const float m = tile[16], r = tile[17];
        const float4* g4 = (const float4*)g1;
        const float4* b4 = (const float4*)be1;
        float4 ga = g4[2 * t], gb = g4[2 * t + 1];
        float4 ba = b4[2 * t], bb = b4[2 * t + 1];
        bf16x8_t o;
        o[0] = (__bf16)((a.x - m) * r * ga.x + ba.x);
        o[1] = (__bf16)((a.y - m) * r * ga.y + ba.y);
        o[2] = (__bf16)((a.z - m) * r * ga.z + ba.z);
        o[3] = (__bf16)((a.w - m) * r * ga.w + ba.w);
        o[4] = (__bf16)((c.x - m) * r * gb.x + bb.x);
        o[5] = (__bf16)((c.y - m) * r * gb.y + bb.y);
        o[6] = (__bf16)((c.z - m) * r * gb.z + bb.z);
        o[7] = (__bf16)((c.w - m) * r * gb.w + bb.w);
        *(bf16x8_t*)(h + (size_t)row * DDIM + t * 8) = o;
    }
}

// ---------------------------------------------------------------- GEMM (B^T)
// C[M,N] = A[M,K] @ Bt[N,K]^T (+bias +Res, relu?).  bf16 in, fp32 acc.
// TMxTN tile, 512 threads (8 waves: 4 wave-tiles x 2 k-halves).
// BK=64 stages, both-sides XOR swizzle; ONE barrier per K-step (circular
// DEPTH=4, refill slot consumed last step), counted vmcnt with end-taper.
// SPLITZ>1: blockIdx.z takes K/SPLITZ slice, writes raw fp32 partials.
template <int TM, int TN, int SPLITZ, int OUT_BF16, int RELU, int RES, int BIAS3>
__global__ __launch_bounds__(512) void gemm_bt(
    const __bf16* __restrict__ A, int K,
    const __bf16* __restrict__ Bt,
    const float* __restrict__ bias, const float* __restrict__ biasB,
    const float* __restrict__ biasC,
    const float* __restrict__ Res,
    void* __restrict__ Cout, int N) {
    constexpr int DEPTH = 4;
    constexpr int STG = (TM + TN) * 64;  // bf16 elems per stage (BK=64)
    __shared__ __align__(16) __bf16 smem[DEPTH * STG];

    const int tid = threadIdx.x;
    const int w = tid >> 6, lane = tid & 63;

    // ---- XCD-aware block swizzle (requires gridDim.x % 8 == 0) ----
    const int gx = gridDim.x, gy = gridDim.y, gz = gridDim.z;
    int l = blockIdx.x + gx * (blockIdx.y + gy * blockIdx.z);
    const int xcd = l & 7;
    int i0 = l >> 3;
    const int by = i0 % gy; i0 /= gy;
    const int bz = i0 % gz; i0 /= gz;
    const int bx = xcd * (gx >> 3) + i0;

    const int m0 = by * TM, n0 = bx * TN;

    const int Kloc = K / SPLITZ;
    const int kb = bz * Kloc;
    const int NK = Kloc / 64;

    constexpr int NT = (TM + TN) / 8;  // 8-row (1KB) chunks per stage
    constexpr int NI = NT / 8;         // chunks per wave

    const int srow = lane >> 3;
    const int sslot = (lane & 7) ^ srow;

    const __bf16* srcs[NI];
    int toff[NI];
    #pragma unroll
    for (int i = 0; i < NI; i++) {
        const int tt = w + 8 * i;
        toff[i] = tt * 512;  // 8 rows * 64 elems
        const int r = tt * 8 + srow;
        srcs[i] = (r < TM)
                      ? A + (size_t)(m0 + r) * K + kb + sslot * 8
                      : Bt + (size_t)(n0 + r - TM) * K + kb + sslot * 8;
    }

    constexpr int MI = TM / 32, NJ = TN / 32;  // wave-tile (TM/2)x(TN/2)
    const int wg = w & 3, kh = w >> 2;         // wave-tile id, k-half id
    const int wm = (wg >> 1) * (TM / 2), wn = (wg & 1) * (TN / 2);
    const int fm = lane & 15, quad = lane >> 4;
    const int f7 = fm & 7;

    const int sl = ((kh * 4 + quad) ^ f7) * 16;
    int aoff[MI], boff[NJ];
    #pragma unroll
    for (int i = 0; i < MI; i++)
        aoff[i] = (wm + 16 * i + fm) * 128 + sl;
    #pragma unroll
    for (int j = 0; j < NJ; j++)
        boff[j] = (TM + wn + 16 * j + fm) * 128 + sl;

    f32x4_t acc[MI][NJ] = {};

    // prologue: fill all DEPTH stages
    #pragma unroll
    for (int d = 0; d < DEPTH; d++)
        #pragma unroll
        for (int i = 0; i < NI; i++)
            GLD16(srcs[i] + d * 64, smem + d * STG + toff[i]);

    for (int ks = 0; ks < NK; ks++) {
        const char* st = (const char*)smem + (ks % DEPTH) * (STG * 2);
        if (ks < NK - 2)
            asm volatile("s_waitcnt vmcnt(%0)\n\ts_barrier"
                         :: "i"((DEPTH - 2) * NI) : "memory");
        else if (ks == NK - 2)
            asm volatile("s_waitcnt vmcnt(%0)\n\ts_barrier"
                         :: "i"(NI) : "memory");
        else
            asm volatile("s_waitcnt vmcnt(0)\n\ts_barrier" ::: "memory");

        if (ks >= 1 && ks + DEPTH - 1 < NK) {
            __bf16* dst = smem + ((ks - 1) % DEPTH) * STG;
            #pragma unroll
            for (int i = 0; i < NI; i++)
                GLD16(srcs[i] + (size_t)(ks + DEPTH - 1) * 64, dst + toff[i]);
        }

        bf16x8_t a[MI], b[NJ];
        #pragma unroll
        for (int i = 0; i < MI; i++)
            a[i] = *(const bf16x8_t*)(st + aoff[i]);
        #pragma unroll
        for (int j = 0; j < NJ; j++)
            b[j] = *(const bf16x8_t*)(st + boff[j]);
        __builtin_amdgcn_s_setprio(1);
        #pragma unroll
        for (int i = 0; i < MI; i++)
            #pragma unroll
            for (int j = 0; j < NJ; j++)
                acc[i][j] = __builtin_amdgcn_mfma_f32_16x16x32_bf16(
                    a[i], b[j], acc[i][j], 0, 0, 0);
        __builtin_amdgcn_s_setprio(0);
    }

    // ---- merge the two k-half accumulators through LDS (reuses stages) ----
    char* mrg = (char*)smem + wg * (MI * NJ * 64 * 16);
    __syncthreads();
    if (kh == 1) {
        #pragma unroll
        for (int i = 0; i < MI; i++)
            #pragma unroll
            for (int j = 0; j < NJ; j++)
                *(f32x4_t*)(mrg + (((i * NJ + j) * 64) + lane) * 16) = acc[i][j];
    }
    __syncthreads();
    if (kh == 1) return;
    #pragma unroll
    for (int i = 0; i < MI; i++)
        #pragma unroll
        for (int j = 0; j < NJ; j++) {
            const f32x4_t p = *(const f32x4_t*)(mrg + (((i * NJ + j) * 64) + lane) * 16);
            acc[i][j][0] += p[0]; acc[i][j][1] += p[1];
            acc[i][j][2] += p[2]; acc[i][j][3] += p[3];
        }

    // epilogue: C/D layout col=fm, row=quad*4+r  (waves 0..3 only)
    if (SPLITZ > 1) {
        float* P = (float*)Cout + (size_t)bz * (gy * TM) * N;
        #pragma unroll
        for (int i = 0; i < MI; i++)
            #pragma unroll
            for (int j = 0; j < NJ; j++) {
                const int col = n0 + wn + 16 * j + fm;
                #pragma unroll
                for (int r = 0; r < 4; r++) {
                    const int row = m0 + wm + 16 * i + quad * 4 + r;
                    P[(size_t)row * N + col] = acc[i][j][r];
                }
            }
    } else {
        #pragma unroll
        for (int i = 0; i < MI; i++)
            #pragma unroll
            for (int j = 0; j < NJ; j++) {
                const int col = n0 + wn + 16 * j + fm;
                float bcol;
                if (BIAS3) {  // per-column q|k|v segment select
                    const float* bp = (col < 2048) ? bias
                                    : (col < 4096) ? biasB : biasC;
                    bcol = bp[col & 2047];
                } else {
                    bcol = bias[col];
                }
                #pragma unroll
                for (int r = 0; r < 4; r++) {
                    const int row = m0 + wm + 16 * i + quad * 4 + r;
                    float val = acc[i][j][r] + bcol;
                    if (RES) val += Res[(size_t)row * N + col];
                    if (RELU) val = fmaxf(val, 0.0f);
                    if (OUT_BF16)
                        ((__bf16*)Cout)[(size_t)row * N + col] = (__bf16)val;
                    else
                        ((float*)Cout)[(size_t)row * N + col] = val;
                }
            }
    }
}

// ---------------------------------------------------------------- split-K sum
template <int NS>
__global__ __launch_bounds__(256) void reduce_splitk(
    const float* __restrict__ part, const float* __restrict__ Res,
    const float* __restrict__ bias, float* __restrict__ out) {
    const int idx = blockIdx.x * 256 + threadIdx.x;  // 0..262143 float4s
    const float4 b4 = ((const float4*)bias)[idx & 511];
    float4 r = ((const float4*)Res)[idx];
    #pragma unroll
    for (int s = 0; s < NS; s++) {
        const float4 p = ((const float4*)part)[(size_t)s * 262144 + idx];
        r.x += p.x; r.y += p.y; r.z += p.z; r.w += p.w;
    }
    r.x += b4.x; r.y += b4.y; r.z += b4.z; r.w += b4.w;
    ((float4*)out)[idx] = r;
}

// ---------------------------------------------------------------- Attention
__global__ __launch_bounds__(128) void attn_kernel(
    const __bf16* __restrict__ qkv, __bf16* __restrict__ o) {
    const int bh = blockIdx.x;  // b*H + h
    const int b = bh >> 4, h = bh & 15;
    const size_t base = (size_t)b * (3 * DDIM) + h * DHEAD;
    const int tid = threadIdx.x;
    __shared__ float ks[DHEAD], vs[DHEAD];
    ks[tid] = (float)qkv[base + DDIM + tid];
    vs[tid] = (float)qkv[base + 2 * DDIM + tid];
    __syncthreads();
    const float a = (float)qkv[base + tid] * 0.08838834764831845f;  // /sqrt(128)
    float den = 0.0f, num = 0.0f;
    #pragma unroll 8
    for (int j = 0; j < DHEAD; j++) {
        float e = __expf(a * ks[j]);
        den += e;
        num += e * vs[j];
    }
    o[(size_t)b * DDIM + h * DHEAD + tid] = (__bf16)(num / den);
}

// ---------------------------------------------------------------- launch
extern "C" void kernel_launch(void* const* d_in, const int* in_sizes, int n_in,
                              void* d_out, int out_size, void* d_ws, size_t ws_size,
                              hipStream_t stream) {
    const float* x   = (const float*)d_in[0];
    const float* Wq  = (const float*)d_in[1];
    const float* bq  = (const float*)d_in[2];
    const float* Wk  = (const float*)d_in[3];
    const float* bk  = (const float*)d_in[4];
    const float* Wv  = (const float*)d_in[5];
    const float* bv  = (const float*)d_in[6];
    const float* Wo  = (const float*)d_in[7];
    const float* bo  = (const float*)d_in[8];
    const float* W1  = (const float*)d_in[9];
    const float* b1  = (const float*)d_in[10];
    const float* W2  = (const float*)d_in[11];
    const float* b2  = (const float*)d_in[12];
    const float* g1  = (const float*)d_in[13];
    const float* be1 = (const float*)d_in[14];
    const float* g2  = (const float*)d_in[15];
    const float* be2 = (const float*)d_in[16];
    float* out = (float*)d_out;

    // ---- workspace layout (bytes), NON-overlapping (~142 MB of 256 MiB) ----
    char* base = (char*)d_ws;
    __bf16* bt_qkv = (__bf16*)(base + 0);             // [6144,2048]  25,165,824
    __bf16* Wot    = (__bf16*)(base + 25165824);      // [2048,2048]   8,388,608
    __bf16* W1t    = (__bf16*)(base + 33554432);      // [8192,2048]  33,554,432
    __bf16* W2t    = (__bf16*)(base + 67108864);      // [2048,8192]  33,554,432
    __bf16* h      = (__bf16*)(base + 100663296);     // [512,2048]    2,097,152
    __bf16* qkv    = (__bf16*)(base + 102760448);     // [512,6144]    6,291,456
    __bf16* ob     = (__bf16*)(base + 109051904);     // [512,2048]    2,097,152
    float*  x1     = (float*)(base + 111149056);      // [512,2048]    4,194,304
    __bf16* h2     = (__bf16*)(base + 115343360);     // [512,2048]    2,097,152
    __bf16* t      = (__bf16*)(base + 117440512);     // [512,8192]    8,388,608
    float*  w2P    = (float*)(base + 125829120);      // [4][512,2048] 16,777,216

    // 1. prep: all weight transposes (bf16 B^T) + h = LN(x)
    prep_kernel<<<3584, 256, 0, stream>>>(Wq, Wk, Wv, Wo, W1, W2, x, g1, be1,
                                          bt_qkv, Wot, W1t, W2t, h);

    // 2. qkv = h @ [Wq|Wk|Wv] + [bq|bk|bv]   -> bf16 [512,6144]  (256 blocks)
    gemm_bt<64, 192, 1, 1, 0, 0, 1><<<dim3(32, 8), 512, 0, stream>>>(
        h, DDIM, bt_qkv, bq, bk, bv, nullptr, qkv, 3 * DDIM);

    // 3. per-sample outer-product attention
    attn_kernel<<<BROWS * HHEADS, 128, 0, stream>>>(qkv, ob);

    // 4. x1 = x + ob @ Wo + bo   (64x64 tiles, 256 blocks)
    gemm_bt<64, 64, 1, 0, 0, 1, 0><<<dim3(32, 8), 512, 0, stream>>>(
        ob, DDIM, Wot, bo, nullptr, nullptr, x, x1, DDIM);

    // 5. h2 = LN(x1)
    ln_kernel<<<BROWS, 256, 0, stream>>>(x1, g2, be2, h2);

    // 6. t = relu(h2 @ W1 + b1)  -> bf16 [512,8192]  (256 blocks)
    gemm_bt<128, 128, 1, 1, 1, 0, 0><<<dim3(64, 4), 512, 0, stream>>>(
        h2, DDIM, W1t, b1, nullptr, nullptr, nullptr, t, 4 * DDIM);

    // 7. w2P = t @ W2 partials   (split-K=4, 256 blocks)
    gemm_bt<128, 128, 4, 0, 0, 0, 0><<<dim3(16, 4, 4), 512, 0, stream>>>(
        t, 4 * DDIM, W2t, nullptr, nullptr, nullptr, nullptr, w2P, DDIM);

    // 8. out = x1 + sum(w2P) + b2
    reduce_splitk<4><<<1024, 256, 0, stream>>>(w2P, x1, b2, out);
}